// Round 4
// baseline (546.147 us; speedup 1.0000x reference)
//
#include <hip/hip_runtime.h>
#include <stdint.h>

// B=4, S=2048, D=1024, H=16, DEPTH=64
// out0: [B,S,D] f32 (8388608), out1: attn [B,H,S,S] f32 (268435456)

typedef float f32x4 __attribute__((ext_vector_type(4)));
typedef __bf16 bf16x8 __attribute__((ext_vector_type(8)));
typedef unsigned short u16x4 __attribute__((ext_vector_type(4)));
typedef unsigned short u16x8 __attribute__((ext_vector_type(8)));

#define LOG2E 1.44269504088896340736f

static __device__ __forceinline__ f32x4 mfma16(bf16x8 a, bf16x8 b, f32x4 c) {
  return __builtin_amdgcn_mfma_f32_16x16x32_bf16(a, b, c, 0, 0, 0);
}
static __device__ __forceinline__ unsigned short bfc(float f) {
  return __builtin_bit_cast(unsigned short, (__bf16)f);
}
static __device__ __forceinline__ float e2(float x) { return __builtin_amdgcn_exp2f(x); }

#define GLDS16(g, l)                                                    \
  __builtin_amdgcn_global_load_lds(                                     \
      (const __attribute__((address_space(1))) void*)(g),               \
      (__attribute__((address_space(3))) void*)(l), 16, 0, 0)

struct Ptr3 { const float* s[3]; unsigned short* d[3]; };
struct Ptr4 { const float* s[4]; unsigned short* d[4]; };
struct QKArgs {
  const unsigned short* A[2];
  const unsigned short* Bt[2];
  const float* bias[2];
  unsigned short* C[2];
};

// ---------------- f32 -> bf16 conversion (all 3 inputs, z-indexed) ----------------
__global__ void cvt3(Ptr3 p) {
  const int z = blockIdx.z;
  const int i = (blockIdx.x * 256 + threadIdx.x) * 4;
  f32x4 v = *(const f32x4*)(const void*)(p.s[z] + i);
  u16x4 o;
  o[0] = bfc(v[0]); o[1] = bfc(v[1]); o[2] = bfc(v[2]); o[3] = bfc(v[3]);
  *(u16x4*)(void*)(p.d[z] + i) = o;
}

// ---------------- W [k][n] f32 -> Wt [n][k] bf16 (all 4, z-indexed) ----------------
__global__ void wtrans4(Ptr4 p) {
  __shared__ float t[32][33];
  const int z = blockIdx.z;
  const float* W = p.s[z];
  unsigned short* Wt = p.d[z];
  const int tx = threadIdx.x & 31, ty = threadIdx.x >> 5;
  const int n0 = blockIdx.x * 32, k0 = blockIdx.y * 32;
#pragma unroll
  for (int i = 0; i < 4; ++i)
    t[ty + i * 8][tx] = W[(size_t)(k0 + ty + i * 8) * 1024 + n0 + tx];
  __syncthreads();
#pragma unroll
  for (int i = 0; i < 4; ++i)
    Wt[(size_t)(n0 + ty + i * 8) * 1024 + k0 + tx] = bfc(t[tx][ty + i * 8]);
}

// ===== shared GEMM core (m97 structure: BK=32, single LDS buffer) =====
#define GEMM_PROLOG(Aptr, Btptr)                                        \
  __shared__ unsigned short sA[128 * 32];                               \
  __shared__ unsigned short sB[128 * 32];                               \
  const int tid = threadIdx.x;                                          \
  const int m0 = blockIdx.x << 7, n0 = blockIdx.y << 7;                 \
  const int w = tid >> 6, lane = tid & 63, g = lane >> 4, r = lane & 15;\
  const int wr = w >> 1, wc = w & 1;                                    \
  const int srow = tid >> 2;                                            \
  const int scol = (tid & 3) << 3;                                      \
  const unsigned short* ga = (Aptr) + (size_t)(m0 + srow) * 1024 + scol;\
  const unsigned short* gb = (Btptr) + (size_t)(n0 + srow) * 1024 + scol;\
  unsigned short* la = sA + tid * 8;                                    \
  unsigned short* lb = sB + tid * 8;

#define GEMM_KLOOP(SWAP)                                                \
  for (int kt = 0; kt < 32; ++kt) {                                     \
    const int ko = kt << 5;                                             \
    GLDS16(ga + ko, la);                                                \
    GLDS16(ga + ko + 64 * 1024, la + 64 * 32);                          \
    GLDS16(gb + ko, lb);                                                \
    GLDS16(gb + ko + 64 * 1024, lb + 64 * 32);                          \
    __syncthreads();                                                    \
    bf16x8 af[4], bfv[4];                                               \
    _Pragma("unroll")                                                   \
    for (int i = 0; i < 4; ++i) {                                       \
      af[i]  = *(const bf16x8*)(const void*)&sA[(wr * 64 + i * 16 + r) * 32 + g * 8]; \
      bfv[i] = *(const bf16x8*)(const void*)&sB[(wc * 64 + i * 16 + r) * 32 + g * 8]; \
    }                                                                   \
    _Pragma("unroll")                                                   \
    for (int i = 0; i < 4; ++i)                                         \
      _Pragma("unroll")                                                 \
      for (int j = 0; j < 4; ++j)                                       \
        acc[i][j] = (SWAP) ? mfma16(bfv[j], af[i], acc[i][j])           \
                           : mfma16(af[i], bfv[j], acc[i][j]);          \
    __syncthreads();                                                    \
  }

// ---------------- Q/K GEMM (z=0: Q pre-scaled by 0.125*log2e, z=1: K) ----------------
__global__ __launch_bounds__(256, 2) void gemm_qk(QKArgs args) {
  const int z = blockIdx.z;
  const f32x4 fz = {0.f, 0.f, 0.f, 0.f};
  f32x4 acc[4][4];
#pragma unroll
  for (int i = 0; i < 4; ++i)
#pragma unroll
    for (int j = 0; j < 4; ++j) acc[i][j] = fz;
  GEMM_PROLOG(args.A[z], args.Bt[z])
  GEMM_KLOOP(1)  // acc[i][j]: regs->n (j*16+g*4+t), lane r->m (i*16+r)
  const float osc = (z == 0) ? (0.125f * LOG2E) : 1.0f;
  unsigned short* Cq = args.C[z];
  const float* bias = args.bias[z];
#pragma unroll
  for (int j = 0; j < 4; ++j) {
    const int nb = n0 + wc * 64 + j * 16 + g * 4;
    const f32x4 b4 = *(const f32x4*)(const void*)(bias + nb);
#pragma unroll
    for (int i = 0; i < 4; ++i) {
      const int m = m0 + wr * 64 + i * 16 + r;
      const int bb = m >> 11, s = m & 2047, hh = nb >> 6, d = nb & 63;
      u16x4 pk;
#pragma unroll
      for (int t = 0; t < 4; ++t) pk[t] = bfc((acc[i][j][t] + b4[t]) * osc);
      *(u16x4*)(void*)(Cq + (size_t)(bb * 16 + hh) * 131072 + (size_t)s * 64 + d) = pk;
    }
  }
}

// ---------------- V GEMM -> transposed per-head [bh][d][s] ----------------
__global__ __launch_bounds__(256, 2) void gemm_v(const unsigned short* __restrict__ A,
                                                 const unsigned short* __restrict__ Bt,
                                                 const float* __restrict__ bias,
                                                 unsigned short* __restrict__ C) {
  const f32x4 fz = {0.f, 0.f, 0.f, 0.f};
  f32x4 acc[4][4];
#pragma unroll
  for (int i = 0; i < 4; ++i)
#pragma unroll
    for (int j = 0; j < 4; ++j) acc[i][j] = fz;
  GEMM_PROLOG(A, Bt)
  GEMM_KLOOP(0)  // acc[i][j]: regs->m (i*16+g*4+t), lane r->n (j*16+r)
#pragma unroll
  for (int j = 0; j < 4; ++j) {
    const int n = n0 + wc * 64 + j * 16 + r;
    const float bv = bias[n];
    const int hh = n >> 6, d = n & 63;
#pragma unroll
    for (int i = 0; i < 4; ++i) {
      const int m = m0 + wr * 64 + i * 16 + g * 4;
      const int bb = m >> 11, s = m & 2047;
      u16x4 pk;
#pragma unroll
      for (int t = 0; t < 4; ++t) pk[t] = bfc(acc[i][j][t] + bv);
      *(u16x4*)(void*)(C + (size_t)(bb * 16 + hh) * 131072 + (size_t)d * 2048 + s) = pk;
    }
  }
}

// ---------------- output GEMM: f32 [m][n], swapped, 16B stores ----------------
__global__ __launch_bounds__(256, 2) void gemm_o(const unsigned short* __restrict__ A,
                                                 const unsigned short* __restrict__ Bt,
                                                 const float* __restrict__ bias,
                                                 float* __restrict__ C) {
  const f32x4 fz = {0.f, 0.f, 0.f, 0.f};
  f32x4 acc[4][4];
#pragma unroll
  for (int i = 0; i < 4; ++i)
#pragma unroll
    for (int j = 0; j < 4; ++j) acc[i][j] = fz;
  GEMM_PROLOG(A, Bt)
  GEMM_KLOOP(1)
#pragma unroll
  for (int j = 0; j < 4; ++j) {
    const int nb = n0 + wc * 64 + j * 16 + g * 4;
    const f32x4 b4 = *(const f32x4*)(const void*)(bias + nb);
#pragma unroll
    for (int i = 0; i < 4; ++i) {
      const int m = m0 + wr * 64 + i * 16 + r;
      f32x4 c;
#pragma unroll
      for (int t = 0; t < 4; ++t) c[t] = acc[i][j][t] + b4[t];
      *(f32x4*)(void*)(C + (size_t)m * 1024 + nb) = c;
    }
  }
}

// ---------------- fused attention ----------------
// QBLK=32: grid 4096 = 64 bh x 64 q-tiles, XCD-swizzled (4096%8==0, bijective).
// 4 waves; wave w owns keys [w*512,(w+1)*512). Q pre-scaled by 0.125*log2e.
// Swapped QK^T (mfma(K,Q)): lane r = q, (g*4+j) = key -> row stats lane-local.
// No max subtraction (|log2-logits| < ~20, exp2 f32-safe); 1/L folded as cL=-log2(L).
// Branchless mask: mp = mask*NEGM (+0 mask -> -0, exp2 unaffected).
// Low VGPR (qf 16 + oacc 32) -> __launch_bounds__(256,4) -> 4 blocks/CU so the
// compute-only pass A of resident blocks overlaps the write-bound pass B of others.
__global__ __launch_bounds__(256, 4) void attn_fused(const unsigned short* __restrict__ Qh,
                                                     const unsigned short* __restrict__ Kh,
                                                     const unsigned short* __restrict__ Vt,
                                                     const float* __restrict__ mask,
                                                     float* __restrict__ attn_out,
                                                     unsigned short* __restrict__ Obuf) {
  __shared__ unsigned short Plds[4][32 * 40];  // pad 40 -> only 2-way conflicts (free)
  __shared__ float Osum[32][68];
  __shared__ float sml[4][32];

  const int blk = (blockIdx.x & 7) * 512 + (blockIdx.x >> 3);  // XCD swizzle
  const int bh = blk >> 6;
  const int q0 = (blk & 63) << 5;
  const int b = bh >> 4, h = bh & 15;
  const int tid = threadIdx.x;
  const int w = tid >> 6, lane = tid & 63, g = lane >> 4, r = lane & 15;
  const float NEGM = -1e9f * LOG2E;

  const unsigned short* Qb = Qh + (size_t)bh * (2048 * 64);
  const unsigned short* Kb = Kh + (size_t)bh * (2048 * 64);
  const unsigned short* Vb = Vt + (size_t)bh * (64 * 2048);
  const float* mb = mask + (size_t)b * 2048;
  const f32x4 fz = {0.f, 0.f, 0.f, 0.f};

  bf16x8 qf[2][2];
#pragma unroll
  for (int qc = 0; qc < 2; ++qc)
#pragma unroll
    for (int hf = 0; hf < 2; ++hf)
      qf[qc][hf] = *(const bf16x8*)(const void*)(Qb + (size_t)(q0 + qc * 16 + r) * 64 + hf * 32 + g * 8);

  float lreg[2] = {0.f, 0.f};

  // ---- pass A: row sums of exp2(logits) over this wave's 512 keys ----
  for (int step = 0; step < 16; ++step) {
    const int kk = (w << 9) + (step << 5);
    bf16x8 kf[2][2];
#pragma unroll
    for (int ks = 0; ks < 2; ++ks)
#pragma unroll
      for (int hf = 0; hf < 2; ++hf)
        kf[ks][hf] = *(const bf16x8*)(const void*)(Kb + (size_t)(kk + ks * 16 + r) * 64 + hf * 32 + g * 8);
    f32x4 mv0 = *(const f32x4*)(const void*)(mb + kk + g * 4);
    f32x4 mv1 = *(const f32x4*)(const void*)(mb + kk + 16 + g * 4);
    f32x4 mp0, mp1;
#pragma unroll
    for (int j = 0; j < 4; ++j) { mp0[j] = mv0[j] * NEGM; mp1[j] = mv1[j] * NEGM; }

#pragma unroll
    for (int qc = 0; qc < 2; ++qc) {
      f32x4 s0 = fz, s1 = fz;
      s0 = mfma16(kf[0][0], qf[qc][0], s0);
      s0 = mfma16(kf[0][1], qf[qc][1], s0);
      s1 = mfma16(kf[1][0], qf[qc][0], s1);
      s1 = mfma16(kf[1][1], qf[qc][1], s1);
      float p = 0.f;
#pragma unroll
      for (int j = 0; j < 4; ++j) p += e2(s0[j] + mp0[j]) + e2(s1[j] + mp1[j]);
      lreg[qc] += p;
    }
  }
#pragma unroll
  for (int qc = 0; qc < 2; ++qc) {
    lreg[qc] += __shfl_xor(lreg[qc], 16);
    lreg[qc] += __shfl_xor(lreg[qc], 32);
  }
  if (lane < 16) {
#pragma unroll
    for (int qc = 0; qc < 2; ++qc) sml[w][qc * 16 + lane] = lreg[qc];
  }
  __syncthreads();
  float cL[2];
#pragma unroll
  for (int qc = 0; qc < 2; ++qc) {
    const int q = qc * 16 + r;
    cL[qc] = -__log2f(sml[0][q] + sml[1][q] + sml[2][q] + sml[3][q]);
  }

  f32x4 oacc[2][4];
#pragma unroll
  for (int i = 0; i < 2; ++i)
#pragma unroll
    for (int j = 0; j < 4; ++j) oacc[i][j] = fz;

  float* ab = attn_out + (size_t)bh * 2048 * 2048;

  // ---- pass B: recompute, write normalized P (nontemporal), accumulate O = P*V ----
  for (int step = 0; step < 16; ++step) {
    const int kk = (w << 9) + (step << 5);
    bf16x8 kf[2][2];
#pragma unroll
    for (int ks = 0; ks < 2; ++ks)
#pragma unroll
      for (int hf = 0; hf < 2; ++hf)
        kf[ks][hf] = *(const bf16x8*)(const void*)(Kb + (size_t)(kk + ks * 16 + r) * 64 + hf * 32 + g * 8);
    f32x4 mv0 = *(const f32x4*)(const void*)(mb + kk + g * 4);
    f32x4 mv1 = *(const f32x4*)(const void*)(mb + kk + 16 + g * 4);
    f32x4 mp[2];
#pragma unroll
    for (int j = 0; j < 4; ++j) { mp[0][j] = mv0[j] * NEGM; mp[1][j] = mv1[j] * NEGM; }

#pragma unroll
    for (int ks = 0; ks < 2; ++ks) {
#pragma unroll
      for (int qc = 0; qc < 2; ++qc) {
        f32x4 s = fz;
        s = mfma16(kf[ks][0], qf[qc][0], s);
        s = mfma16(kf[ks][1], qf[qc][1], s);
        f32x4 pv;
        u16x4 pb;
#pragma unroll
        for (int j = 0; j < 4; ++j) {
          const float val = e2(s[j] + mp[ks][j] + cL[qc]);
          pv[j] = val;
          pb[j] = bfc(val);
        }
        __builtin_nontemporal_store(
            pv, (f32x4*)(void*)(ab + (size_t)(q0 + qc * 16 + r) * 2048 + kk + ks * 16 + g * 4));
        *(u16x4*)(void*)(&Plds[w][(qc * 16 + r) * 40 + ks * 16 + g * 4]) = pb;
      }
    }
    bf16x8 vf[4];
#pragma unroll
    for (int dn = 0; dn < 4; ++dn)
      vf[dn] = *(const bf16x8*)(const void*)(Vb + (size_t)(dn * 16 + r) * 2048 + kk + g * 8);
#pragma unroll
    for (int qs = 0; qs < 2; ++qs) {
      const bf16x8 pa = *(const bf16x8*)(const void*)(&Plds[w][(qs * 16 + r) * 40 + g * 8]);
#pragma unroll
      for (int dn = 0; dn < 4; ++dn) oacc[qs][dn] = mfma16(pa, vf[dn], oacc[qs][dn]);
    }
  }

  // ---- reduce O across waves (disjoint 512-key partials) ----
  for (int wv = 0; wv < 4; ++wv) {
    if (w == wv) {
#pragma unroll
      for (int qs = 0; qs < 2; ++qs)
#pragma unroll
        for (int dn = 0; dn < 4; ++dn)
#pragma unroll
          for (int j = 0; j < 4; ++j) {
            const int q = qs * 16 + g * 4 + j, d = dn * 16 + r;
            if (wv == 0) Osum[q][d] = oacc[qs][dn][j];
            else         Osum[q][d] += oacc[qs][dn][j];
          }
    }
    __syncthreads();
  }
  const int orow = tid >> 3, oc0 = (tid & 7) << 3;
  u16x8 pk;
#pragma unroll
  for (int j = 0; j < 8; ++j) pk[j] = bfc(Osum[orow][oc0 + j]);
  *(u16x8*)(void*)(Obuf + (size_t)(b * 2048 + q0 + orow) * 1024 + h * 64 + oc0) = pk;
}

// ---------------- launch ----------------
extern "C" void kernel_launch(void* const* d_in, const int* in_sizes, int n_in,
                              void* d_out, int out_size, void* d_ws, size_t ws_size,
                              hipStream_t stream) {
  const float* query = (const float*)d_in[0];
  const float* key_  = (const float*)d_in[1];
  const float* value = (const float*)d_in[2];
  const float* mask  = (const float*)d_in[3];
  const float* Wq = (const float*)d_in[4];
  const float* bq = (const float*)d_in[5];
  const float* Wk = (const float*)d_in[6];
  const float* bk = (const float*)d_in[7];
  const float* Wv = (const float*)d_in[8];
  const float* bv = (const float*)d_in[9];
  const float* Wo = (const float*)d_in[10];
  const float* bo = (const float*)d_in[11];

  uint8_t* ws = (uint8_t*)d_ws;
  unsigned short* XQ  = (unsigned short*)(ws);             // 16 MB bf16
  unsigned short* XK  = (unsigned short*)(ws + 16777216);
  unsigned short* XV  = (unsigned short*)(ws + 33554432);
  unsigned short* WTQ = (unsigned short*)(ws + 50331648);  // 2 MB each, [n][k]
  unsigned short* WTK = (unsigned short*)(ws + 52428800);
  unsigned short* WTV = (unsigned short*)(ws + 54525952);
  unsigned short* WTO = (unsigned short*)(ws + 56623104);
  unsigned short* QH  = (unsigned short*)(ws + 58720256);  // [bh][s][d] (pre-scaled)
  unsigned short* KH  = (unsigned short*)(ws + 75497472);  // [bh][s][d]
  unsigned short* VT  = (unsigned short*)(ws + 92274688);  // [bh][d][s]
  unsigned short* OB  = XQ;  // alias: XQ dead after gemm_qk

  float* outp = (float*)d_out;
  float* attnp = outp + 8388608;

  Ptr3 pc = {{query, key_, value}, {XQ, XK, XV}};
  cvt3<<<dim3(8192, 1, 3), 256, 0, stream>>>(pc);
  Ptr4 pw = {{Wq, Wk, Wv, Wo}, {WTQ, WTK, WTV, WTO}};
  wtrans4<<<dim3(32, 32, 4), 256, 0, stream>>>(pw);
  QKArgs qk = {{XQ, XK}, {WTQ, WTK}, {bq, bk}, {QH, KH}};
  gemm_qk<<<dim3(64, 8, 2), 256, 0, stream>>>(qk);
  gemm_v<<<dim3(64, 8), 256, 0, stream>>>(XV, WTV, bv, VT);
  attn_fused<<<4096, 256, 0, stream>>>(QH, KH, VT, mask, attnp, OB);
  gemm_o<<<dim3(64, 8), 256, 0, stream>>>(OB, WTO, bo, outp);
}

// Round 5
// 507.023 us; speedup vs baseline: 1.0772x; 1.0772x over previous
//
#include <hip/hip_runtime.h>
#include <stdint.h>

// B=4, S=2048, D=1024, H=16, DEPTH=64
// out0: [B,S,D] f32 (8388608), out1: attn [B,H,S,S] f32 (268435456)

typedef float f32x4 __attribute__((ext_vector_type(4)));
typedef __bf16 bf16x8 __attribute__((ext_vector_type(8)));
typedef unsigned short u16x4 __attribute__((ext_vector_type(4)));
typedef unsigned short u16x8 __attribute__((ext_vector_type(8)));

#define LOG2E 1.44269504088896340736f

static __device__ __forceinline__ f32x4 mfma16(bf16x8 a, bf16x8 b, f32x4 c) {
  return __builtin_amdgcn_mfma_f32_16x16x32_bf16(a, b, c, 0, 0, 0);
}
static __device__ __forceinline__ unsigned short bfc(float f) {
  return __builtin_bit_cast(unsigned short, (__bf16)f);
}
static __device__ __forceinline__ float e2(float x) { return __builtin_amdgcn_exp2f(x); }

#define GLDS16(g, l)                                                    \
  __builtin_amdgcn_global_load_lds(                                     \
      (const __attribute__((address_space(1))) void*)(g),               \
      (__attribute__((address_space(3))) void*)(l), 16, 0, 0)

struct Ptr3 { const float* s[3]; unsigned short* d[3]; };
struct Ptr4 { const float* s[4]; unsigned short* d[4]; };
struct QKArgs {
  const unsigned short* A[2];
  const unsigned short* Bt[2];
  const float* bias[2];
  unsigned short* C[2];
};

// ---------------- f32 -> bf16 conversion (all 3 inputs, z-indexed) ----------------
__global__ void cvt3(Ptr3 p) {
  const int z = blockIdx.z;
  const int i = (blockIdx.x * 256 + threadIdx.x) * 4;
  f32x4 v = *(const f32x4*)(const void*)(p.s[z] + i);
  u16x4 o;
  o[0] = bfc(v[0]); o[1] = bfc(v[1]); o[2] = bfc(v[2]); o[3] = bfc(v[3]);
  *(u16x4*)(void*)(p.d[z] + i) = o;
}

// ---------------- W [k][n] f32 -> Wt [n][k] bf16 (all 4, z-indexed) ----------------
__global__ void wtrans4(Ptr4 p) {
  __shared__ float t[32][33];
  const int z = blockIdx.z;
  const float* W = p.s[z];
  unsigned short* Wt = p.d[z];
  const int tx = threadIdx.x & 31, ty = threadIdx.x >> 5;
  const int n0 = blockIdx.x * 32, k0 = blockIdx.y * 32;
#pragma unroll
  for (int i = 0; i < 4; ++i)
    t[ty + i * 8][tx] = W[(size_t)(k0 + ty + i * 8) * 1024 + n0 + tx];
  __syncthreads();
#pragma unroll
  for (int i = 0; i < 4; ++i)
    Wt[(size_t)(n0 + ty + i * 8) * 1024 + k0 + tx] = bfc(t[tx][ty + i * 8]);
}

// ===== shared GEMM core (m97 structure: BK=32, single LDS buffer) =====
#define GEMM_PROLOG(Aptr, Btptr)                                        \
  __shared__ unsigned short sA[128 * 32];                               \
  __shared__ unsigned short sB[128 * 32];                               \
  const int tid = threadIdx.x;                                          \
  const int m0 = blockIdx.x << 7, n0 = blockIdx.y << 7;                 \
  const int w = tid >> 6, lane = tid & 63, g = lane >> 4, r = lane & 15;\
  const int wr = w >> 1, wc = w & 1;                                    \
  const int srow = tid >> 2;                                            \
  const int scol = (tid & 3) << 3;                                      \
  const unsigned short* ga = (Aptr) + (size_t)(m0 + srow) * 1024 + scol;\
  const unsigned short* gb = (Btptr) + (size_t)(n0 + srow) * 1024 + scol;\
  unsigned short* la = sA + tid * 8;                                    \
  unsigned short* lb = sB + tid * 8;

#define GEMM_KLOOP(SWAP)                                                \
  for (int kt = 0; kt < 32; ++kt) {                                     \
    const int ko = kt << 5;                                             \
    GLDS16(ga + ko, la);                                                \
    GLDS16(ga + ko + 64 * 1024, la + 64 * 32);                          \
    GLDS16(gb + ko, lb);                                                \
    GLDS16(gb + ko + 64 * 1024, lb + 64 * 32);                          \
    __syncthreads();                                                    \
    bf16x8 af[4], bfv[4];                                               \
    _Pragma("unroll")                                                   \
    for (int i = 0; i < 4; ++i) {                                       \
      af[i]  = *(const bf16x8*)(const void*)&sA[(wr * 64 + i * 16 + r) * 32 + g * 8]; \
      bfv[i] = *(const bf16x8*)(const void*)&sB[(wc * 64 + i * 16 + r) * 32 + g * 8]; \
    }                                                                   \
    _Pragma("unroll")                                                   \
    for (int i = 0; i < 4; ++i)                                         \
      _Pragma("unroll")                                                 \
      for (int j = 0; j < 4; ++j)                                       \
        acc[i][j] = (SWAP) ? mfma16(bfv[j], af[i], acc[i][j])           \
                           : mfma16(af[i], bfv[j], acc[i][j]);          \
    __syncthreads();                                                    \
  }

// ---------------- Q/K GEMM (z=0: Q pre-scaled by 0.125*log2e, z=1: K) ----------------
__global__ __launch_bounds__(256, 2) void gemm_qk(QKArgs args) {
  const int z = blockIdx.z;
  const f32x4 fz = {0.f, 0.f, 0.f, 0.f};
  f32x4 acc[4][4];
#pragma unroll
  for (int i = 0; i < 4; ++i)
#pragma unroll
    for (int j = 0; j < 4; ++j) acc[i][j] = fz;
  GEMM_PROLOG(args.A[z], args.Bt[z])
  GEMM_KLOOP(1)  // acc[i][j]: regs->n (j*16+g*4+t), lane r->m (i*16+r)
  const float osc = (z == 0) ? (0.125f * LOG2E) : 1.0f;
  unsigned short* Cq = args.C[z];
  const float* bias = args.bias[z];
#pragma unroll
  for (int j = 0; j < 4; ++j) {
    const int nb = n0 + wc * 64 + j * 16 + g * 4;
    const f32x4 b4 = *(const f32x4*)(const void*)(bias + nb);
#pragma unroll
    for (int i = 0; i < 4; ++i) {
      const int m = m0 + wr * 64 + i * 16 + r;
      const int bb = m >> 11, s = m & 2047, hh = nb >> 6, d = nb & 63;
      u16x4 pk;
#pragma unroll
      for (int t = 0; t < 4; ++t) pk[t] = bfc((acc[i][j][t] + b4[t]) * osc);
      *(u16x4*)(void*)(Cq + (size_t)(bb * 16 + hh) * 131072 + (size_t)s * 64 + d) = pk;
    }
  }
}

// ---------------- V GEMM -> transposed per-head [bh][d][s] ----------------
__global__ __launch_bounds__(256, 2) void gemm_v(const unsigned short* __restrict__ A,
                                                 const unsigned short* __restrict__ Bt,
                                                 const float* __restrict__ bias,
                                                 unsigned short* __restrict__ C) {
  const f32x4 fz = {0.f, 0.f, 0.f, 0.f};
  f32x4 acc[4][4];
#pragma unroll
  for (int i = 0; i < 4; ++i)
#pragma unroll
    for (int j = 0; j < 4; ++j) acc[i][j] = fz;
  GEMM_PROLOG(A, Bt)
  GEMM_KLOOP(0)  // acc[i][j]: regs->m (i*16+g*4+t), lane r->n (j*16+r)
#pragma unroll
  for (int j = 0; j < 4; ++j) {
    const int n = n0 + wc * 64 + j * 16 + r;
    const float bv = bias[n];
    const int hh = n >> 6, d = n & 63;
#pragma unroll
    for (int i = 0; i < 4; ++i) {
      const int m = m0 + wr * 64 + i * 16 + g * 4;
      const int bb = m >> 11, s = m & 2047;
      u16x4 pk;
#pragma unroll
      for (int t = 0; t < 4; ++t) pk[t] = bfc(acc[i][j][t] + bv);
      *(u16x4*)(void*)(C + (size_t)(bb * 16 + hh) * 131072 + (size_t)d * 2048 + s) = pk;
    }
  }
}

// ---------------- output GEMM: f32 [m][n], swapped, 16B stores ----------------
__global__ __launch_bounds__(256, 2) void gemm_o(const unsigned short* __restrict__ A,
                                                 const unsigned short* __restrict__ Bt,
                                                 const float* __restrict__ bias,
                                                 float* __restrict__ C) {
  const f32x4 fz = {0.f, 0.f, 0.f, 0.f};
  f32x4 acc[4][4];
#pragma unroll
  for (int i = 0; i < 4; ++i)
#pragma unroll
    for (int j = 0; j < 4; ++j) acc[i][j] = fz;
  GEMM_PROLOG(A, Bt)
  GEMM_KLOOP(1)
#pragma unroll
  for (int j = 0; j < 4; ++j) {
    const int nb = n0 + wc * 64 + j * 16 + g * 4;
    const f32x4 b4 = *(const f32x4*)(const void*)(bias + nb);
#pragma unroll
    for (int i = 0; i < 4; ++i) {
      const int m = m0 + wr * 64 + i * 16 + r;
      f32x4 c;
#pragma unroll
      for (int t = 0; t < 4; ++t) c[t] = acc[i][j][t] + b4[t];
      *(f32x4*)(void*)(C + (size_t)m * 1024 + nb) = c;
    }
  }
}

// ---------------- fused attention (R1 structure + VALU trims) ----------------
// QBLK=64: grid 2048 = 64 bh x 32 q-tiles, XCD-swizzled. 4 waves, wave w owns keys
// [w*512,(w+1)*512). Q PRE-SCALED by 0.125*log2e in gemm_qk. Swapped QK^T (mfma(K,Q)):
// lane r = q, (g*4+j) = key -> softmax stats lane-local per q. No max subtraction
// (|log2-logits| < ~20, exp2 f32-safe). 1/L folded into exponent as cL = -log2(L).
// Branchless mask: mp = mask*NEGM (+0 -> -0, exp2 unaffected).
// Low-VGPR pass A (immediate s0/s1 consumption) — R2's 8-live-acc variant regressed.
__global__ __launch_bounds__(256, 2) void attn_fused(const unsigned short* __restrict__ Qh,
                                                     const unsigned short* __restrict__ Kh,
                                                     const unsigned short* __restrict__ Vt,
                                                     const float* __restrict__ mask,
                                                     float* __restrict__ attn_out,
                                                     unsigned short* __restrict__ Obuf) {
  __shared__ unsigned short Plds[4][64 * 40];  // pad 40 -> only 2-way conflicts (free)
  __shared__ float Osum[64][68];
  __shared__ float sml[4][64];

  const int blk = (blockIdx.x & 7) * 256 + (blockIdx.x >> 3);  // XCD swizzle (2048%8==0)
  const int bh = blk >> 5;
  const int q0 = (blk & 31) << 6;
  const int b = bh >> 4, h = bh & 15;
  const int tid = threadIdx.x;
  const int w = tid >> 6, lane = tid & 63, g = lane >> 4, r = lane & 15;
  const float NEGM = -1e9f * LOG2E;

  const unsigned short* Qb = Qh + (size_t)bh * (2048 * 64);
  const unsigned short* Kb = Kh + (size_t)bh * (2048 * 64);
  const unsigned short* Vb = Vt + (size_t)bh * (64 * 2048);
  const float* mb = mask + (size_t)b * 2048;
  const f32x4 fz = {0.f, 0.f, 0.f, 0.f};

  bf16x8 qf[4][2];
#pragma unroll
  for (int qc = 0; qc < 4; ++qc)
#pragma unroll
    for (int hf = 0; hf < 2; ++hf)
      qf[qc][hf] = *(const bf16x8*)(const void*)(Qb + (size_t)(q0 + qc * 16 + r) * 64 + hf * 32 + g * 8);

  float lreg[4] = {0.f, 0.f, 0.f, 0.f};

  // ---- pass A: row sums of exp2(logits) over this wave's 512 keys ----
  for (int step = 0; step < 16; ++step) {
    const int kk = (w << 9) + (step << 5);
    bf16x8 kf[2][2];
#pragma unroll
    for (int ks = 0; ks < 2; ++ks)
#pragma unroll
      for (int hf = 0; hf < 2; ++hf)
        kf[ks][hf] = *(const bf16x8*)(const void*)(Kb + (size_t)(kk + ks * 16 + r) * 64 + hf * 32 + g * 8);
    f32x4 mv0 = *(const f32x4*)(const void*)(mb + kk + g * 4);
    f32x4 mv1 = *(const f32x4*)(const void*)(mb + kk + 16 + g * 4);
    f32x4 mp0, mp1;
#pragma unroll
    for (int j = 0; j < 4; ++j) { mp0[j] = mv0[j] * NEGM; mp1[j] = mv1[j] * NEGM; }

#pragma unroll
    for (int qc = 0; qc < 4; ++qc) {
      f32x4 s0 = fz, s1 = fz;
      s0 = mfma16(kf[0][0], qf[qc][0], s0);
      s0 = mfma16(kf[0][1], qf[qc][1], s0);
      s1 = mfma16(kf[1][0], qf[qc][0], s1);
      s1 = mfma16(kf[1][1], qf[qc][1], s1);
      float p = 0.f;
#pragma unroll
      for (int j = 0; j < 4; ++j) p += e2(s0[j] + mp0[j]) + e2(s1[j] + mp1[j]);
      lreg[qc] += p;
    }
  }
#pragma unroll
  for (int qc = 0; qc < 4; ++qc) {
    lreg[qc] += __shfl_xor(lreg[qc], 16);
    lreg[qc] += __shfl_xor(lreg[qc], 32);
  }
  if (lane < 16) {
#pragma unroll
    for (int qc = 0; qc < 4; ++qc) sml[w][qc * 16 + lane] = lreg[qc];
  }
  __syncthreads();
  float cL[4];
#pragma unroll
  for (int qc = 0; qc < 4; ++qc) {
    const int q = qc * 16 + r;
    cL[qc] = -__log2f(sml[0][q] + sml[1][q] + sml[2][q] + sml[3][q]);
  }

  f32x4 oacc[4][4];
#pragma unroll
  for (int i = 0; i < 4; ++i)
#pragma unroll
    for (int j = 0; j < 4; ++j) oacc[i][j] = fz;

  float* ab = attn_out + (size_t)bh * 2048 * 2048;

  // ---- pass B: recompute, write normalized P (nontemporal), accumulate O = P*V ----
  for (int step = 0; step < 16; ++step) {
    const int kk = (w << 9) + (step << 5);
    bf16x8 kf[2][2];
#pragma unroll
    for (int ks = 0; ks < 2; ++ks)
#pragma unroll
      for (int hf = 0; hf < 2; ++hf)
        kf[ks][hf] = *(const bf16x8*)(const void*)(Kb + (size_t)(kk + ks * 16 + r) * 64 + hf * 32 + g * 8);
    f32x4 mv0 = *(const f32x4*)(const void*)(mb + kk + g * 4);
    f32x4 mv1 = *(const f32x4*)(const void*)(mb + kk + 16 + g * 4);
    f32x4 mp[2];
#pragma unroll
    for (int j = 0; j < 4; ++j) { mp[0][j] = mv0[j] * NEGM; mp[1][j] = mv1[j] * NEGM; }

#pragma unroll
    for (int ks = 0; ks < 2; ++ks) {
#pragma unroll
      for (int qc = 0; qc < 4; ++qc) {
        f32x4 s = fz;
        s = mfma16(kf[ks][0], qf[qc][0], s);
        s = mfma16(kf[ks][1], qf[qc][1], s);
        f32x4 pv;
        u16x4 pb;
#pragma unroll
        for (int j = 0; j < 4; ++j) {
          const float val = e2(s[j] + mp[ks][j] + cL[qc]);
          pv[j] = val;
          pb[j] = bfc(val);
        }
        __builtin_nontemporal_store(
            pv, (f32x4*)(void*)(ab + (size_t)(q0 + qc * 16 + r) * 2048 + kk + ks * 16 + g * 4));
        *(u16x4*)(void*)(&Plds[w][(qc * 16 + r) * 40 + ks * 16 + g * 4]) = pb;
      }
    }
    bf16x8 vf[4];
#pragma unroll
    for (int dn = 0; dn < 4; ++dn)
      vf[dn] = *(const bf16x8*)(const void*)(Vb + (size_t)(dn * 16 + r) * 2048 + kk + g * 8);
#pragma unroll
    for (int qs = 0; qs < 4; ++qs) {
      const bf16x8 pa = *(const bf16x8*)(const void*)(&Plds[w][(qs * 16 + r) * 40 + g * 8]);
#pragma unroll
      for (int dn = 0; dn < 4; ++dn) oacc[qs][dn] = mfma16(pa, vf[dn], oacc[qs][dn]);
    }
  }

  // ---- reduce O across waves (disjoint 512-key partials) ----
  for (int wv = 0; wv < 4; ++wv) {
    if (w == wv) {
#pragma unroll
      for (int qs = 0; qs < 4; ++qs)
#pragma unroll
        for (int dn = 0; dn < 4; ++dn)
#pragma unroll
          for (int j = 0; j < 4; ++j) {
            const int q = qs * 16 + g * 4 + j, d = dn * 16 + r;
            if (wv == 0) Osum[q][d] = oacc[qs][dn][j];
            else         Osum[q][d] += oacc[qs][dn][j];
          }
    }
    __syncthreads();
  }
  const int orow = tid >> 2, oc0 = (tid & 3) << 4;
#pragma unroll
  for (int half = 0; half < 2; ++half) {
    u16x8 pk;
#pragma unroll
    for (int j = 0; j < 8; ++j) pk[j] = bfc(Osum[orow][oc0 + half * 8 + j]);
    *(u16x8*)(void*)(Obuf + (size_t)(b * 2048 + q0 + orow) * 1024 + h * 64 + oc0 + half * 8) = pk;
  }
}

// ---------------- launch ----------------
extern "C" void kernel_launch(void* const* d_in, const int* in_sizes, int n_in,
                              void* d_out, int out_size, void* d_ws, size_t ws_size,
                              hipStream_t stream) {
  const float* query = (const float*)d_in[0];
  const float* key_  = (const float*)d_in[1];
  const float* value = (const float*)d_in[2];
  const float* mask  = (const float*)d_in[3];
  const float* Wq = (const float*)d_in[4];
  const float* bq = (const float*)d_in[5];
  const float* Wk = (const float*)d_in[6];
  const float* bk = (const float*)d_in[7];
  const float* Wv = (const float*)d_in[8];
  const float* bv = (const float*)d_in[9];
  const float* Wo = (const float*)d_in[10];
  const float* bo = (const float*)d_in[11];

  uint8_t* ws = (uint8_t*)d_ws;
  unsigned short* XQ  = (unsigned short*)(ws);             // 16 MB bf16
  unsigned short* XK  = (unsigned short*)(ws + 16777216);
  unsigned short* XV  = (unsigned short*)(ws + 33554432);
  unsigned short* WTQ = (unsigned short*)(ws + 50331648);  // 2 MB each, [n][k]
  unsigned short* WTK = (unsigned short*)(ws + 52428800);
  unsigned short* WTV = (unsigned short*)(ws + 54525952);
  unsigned short* WTO = (unsigned short*)(ws + 56623104);
  unsigned short* QH  = (unsigned short*)(ws + 58720256);  // [bh][s][d] (pre-scaled)
  unsigned short* KH  = (unsigned short*)(ws + 75497472);  // [bh][s][d]
  unsigned short* VT  = (unsigned short*)(ws + 92274688);  // [bh][d][s]
  unsigned short* OB  = XQ;  // alias: XQ dead after gemm_qk

  float* outp = (float*)d_out;
  float* attnp = outp + 8388608;

  Ptr3 pc = {{query, key_, value}, {XQ, XK, XV}};
  cvt3<<<dim3(8192, 1, 3), 256, 0, stream>>>(pc);
  Ptr4 pw = {{Wq, Wk, Wv, Wo}, {WTQ, WTK, WTV, WTO}};
  wtrans4<<<dim3(32, 32, 4), 256, 0, stream>>>(pw);
  QKArgs qk = {{XQ, XK}, {WTQ, WTK}, {bq, bk}, {QH, KH}};
  gemm_qk<<<dim3(64, 8, 2), 256, 0, stream>>>(qk);
  gemm_v<<<dim3(64, 8), 256, 0, stream>>>(XV, WTV, bv, VT);
  attn_fused<<<2048, 256, 0, stream>>>(QH, KH, VT, mask, attnp, OB);
  gemm_o<<<dim3(64, 8), 256, 0, stream>>>(OB, WTO, bo, outp);
}

// Round 6
// 491.073 us; speedup vs baseline: 1.1121x; 1.0325x over previous
//
#include <hip/hip_runtime.h>
#include <stdint.h>

// B=4, S=2048, D=1024, H=16, DEPTH=64
// out0: [B,S,D] f32 (8388608), out1: attn [B,H,S,S] f32 (268435456)

typedef float f32x4 __attribute__((ext_vector_type(4)));
typedef __bf16 bf16x8 __attribute__((ext_vector_type(8)));
typedef unsigned short u16x4 __attribute__((ext_vector_type(4)));
typedef unsigned short u16x8 __attribute__((ext_vector_type(8)));

#define LOG2E 1.44269504088896340736f

static __device__ __forceinline__ f32x4 mfma16(bf16x8 a, bf16x8 b, f32x4 c) {
  return __builtin_amdgcn_mfma_f32_16x16x32_bf16(a, b, c, 0, 0, 0);
}
static __device__ __forceinline__ unsigned short bfc(float f) {
  return __builtin_bit_cast(unsigned short, (__bf16)f);
}
static __device__ __forceinline__ float e2(float x) { return __builtin_amdgcn_exp2f(x); }

#define GLDS16(g, l)                                                    \
  __builtin_amdgcn_global_load_lds(                                     \
      (const __attribute__((address_space(1))) void*)(g),               \
      (__attribute__((address_space(3))) void*)(l), 16, 0, 0)

struct Ptr3 { const float* s[3]; unsigned short* d[3]; };
struct Ptr4 { const float* s[4]; unsigned short* d[4]; };
struct QKArgs {
  const unsigned short* A[2];
  const unsigned short* Bt[2];
  const float* bias[2];
  unsigned short* C[2];
};

// ---------------- f32 -> bf16 conversion (all 3 inputs, z-indexed) ----------------
__global__ void cvt3(Ptr3 p) {
  const int z = blockIdx.z;
  const int i = (blockIdx.x * 256 + threadIdx.x) * 4;
  f32x4 v = *(const f32x4*)(const void*)(p.s[z] + i);
  u16x4 o;
  o[0] = bfc(v[0]); o[1] = bfc(v[1]); o[2] = bfc(v[2]); o[3] = bfc(v[3]);
  *(u16x4*)(void*)(p.d[z] + i) = o;
}

// ---------------- W [k][n] f32 -> Wt [n][k] bf16 (all 4, z-indexed) ----------------
__global__ void wtrans4(Ptr4 p) {
  __shared__ float t[32][33];
  const int z = blockIdx.z;
  const float* W = p.s[z];
  unsigned short* Wt = p.d[z];
  const int tx = threadIdx.x & 31, ty = threadIdx.x >> 5;
  const int n0 = blockIdx.x * 32, k0 = blockIdx.y * 32;
#pragma unroll
  for (int i = 0; i < 4; ++i)
    t[ty + i * 8][tx] = W[(size_t)(k0 + ty + i * 8) * 1024 + n0 + tx];
  __syncthreads();
#pragma unroll
  for (int i = 0; i < 4; ++i)
    Wt[(size_t)(n0 + ty + i * 8) * 1024 + k0 + tx] = bfc(t[tx][ty + i * 8]);
}

// ===== shared GEMM core (m97 structure: BK=32, single LDS buffer) =====
#define GEMM_PROLOG(Aptr, Btptr)                                        \
  __shared__ unsigned short sA[128 * 32];                               \
  __shared__ unsigned short sB[128 * 32];                               \
  const int tid = threadIdx.x;                                          \
  const int m0 = blockIdx.x << 7, n0 = blockIdx.y << 7;                 \
  const int w = tid >> 6, lane = tid & 63, g = lane >> 4, r = lane & 15;\
  const int wr = w >> 1, wc = w & 1;                                    \
  const int srow = tid >> 2;                                            \
  const int scol = (tid & 3) << 3;                                      \
  const unsigned short* ga = (Aptr) + (size_t)(m0 + srow) * 1024 + scol;\
  const unsigned short* gb = (Btptr) + (size_t)(n0 + srow) * 1024 + scol;\
  unsigned short* la = sA + tid * 8;                                    \
  unsigned short* lb = sB + tid * 8;

#define GEMM_KLOOP(SWAP)                                                \
  for (int kt = 0; kt < 32; ++kt) {                                     \
    const int ko = kt << 5;                                             \
    GLDS16(ga + ko, la);                                                \
    GLDS16(ga + ko + 64 * 1024, la + 64 * 32);                          \
    GLDS16(gb + ko, lb);                                                \
    GLDS16(gb + ko + 64 * 1024, lb + 64 * 32);                          \
    __syncthreads();                                                    \
    bf16x8 af[4], bfv[4];                                               \
    _Pragma("unroll")                                                   \
    for (int i = 0; i < 4; ++i) {                                       \
      af[i]  = *(const bf16x8*)(const void*)&sA[(wr * 64 + i * 16 + r) * 32 + g * 8]; \
      bfv[i] = *(const bf16x8*)(const void*)&sB[(wc * 64 + i * 16 + r) * 32 + g * 8]; \
    }                                                                   \
    _Pragma("unroll")                                                   \
    for (int i = 0; i < 4; ++i)                                         \
      _Pragma("unroll")                                                 \
      for (int j = 0; j < 4; ++j)                                       \
        acc[i][j] = (SWAP) ? mfma16(bfv[j], af[i], acc[i][j])           \
                           : mfma16(af[i], bfv[j], acc[i][j]);          \
    __syncthreads();                                                    \
  }

// ---------------- Q/K GEMM (z=0: Q pre-scaled by 0.125*log2e, z=1: K) ----------------
__global__ __launch_bounds__(256, 2) void gemm_qk(QKArgs args) {
  const int z = blockIdx.z;
  const f32x4 fz = {0.f, 0.f, 0.f, 0.f};
  f32x4 acc[4][4];
#pragma unroll
  for (int i = 0; i < 4; ++i)
#pragma unroll
    for (int j = 0; j < 4; ++j) acc[i][j] = fz;
  GEMM_PROLOG(args.A[z], args.Bt[z])
  GEMM_KLOOP(1)  // acc[i][j]: regs->n (j*16+g*4+t), lane r->m (i*16+r)
  const float osc = (z == 0) ? (0.125f * LOG2E) : 1.0f;
  unsigned short* Cq = args.C[z];
  const float* bias = args.bias[z];
#pragma unroll
  for (int j = 0; j < 4; ++j) {
    const int nb = n0 + wc * 64 + j * 16 + g * 4;
    const f32x4 b4 = *(const f32x4*)(const void*)(bias + nb);
#pragma unroll
    for (int i = 0; i < 4; ++i) {
      const int m = m0 + wr * 64 + i * 16 + r;
      const int bb = m >> 11, s = m & 2047, hh = nb >> 6, d = nb & 63;
      u16x4 pk;
#pragma unroll
      for (int t = 0; t < 4; ++t) pk[t] = bfc((acc[i][j][t] + b4[t]) * osc);
      *(u16x4*)(void*)(Cq + (size_t)(bb * 16 + hh) * 131072 + (size_t)s * 64 + d) = pk;
    }
  }
}

// ---------------- V GEMM -> transposed per-head [bh][d][s] ----------------
__global__ __launch_bounds__(256, 2) void gemm_v(const unsigned short* __restrict__ A,
                                                 const unsigned short* __restrict__ Bt,
                                                 const float* __restrict__ bias,
                                                 unsigned short* __restrict__ C) {
  const f32x4 fz = {0.f, 0.f, 0.f, 0.f};
  f32x4 acc[4][4];
#pragma unroll
  for (int i = 0; i < 4; ++i)
#pragma unroll
    for (int j = 0; j < 4; ++j) acc[i][j] = fz;
  GEMM_PROLOG(A, Bt)
  GEMM_KLOOP(0)  // acc[i][j]: regs->m (i*16+g*4+t), lane r->n (j*16+r)
#pragma unroll
  for (int j = 0; j < 4; ++j) {
    const int n = n0 + wc * 64 + j * 16 + r;
    const float bv = bias[n];
    const int hh = n >> 6, d = n & 63;
#pragma unroll
    for (int i = 0; i < 4; ++i) {
      const int m = m0 + wr * 64 + i * 16 + g * 4;
      const int bb = m >> 11, s = m & 2047;
      u16x4 pk;
#pragma unroll
      for (int t = 0; t < 4; ++t) pk[t] = bfc(acc[i][j][t] + bv);
      *(u16x4*)(void*)(C + (size_t)(bb * 16 + hh) * 131072 + (size_t)d * 2048 + s) = pk;
    }
  }
}

// ---------------- output GEMM: f32 [m][n], swapped, 16B stores ----------------
__global__ __launch_bounds__(256, 2) void gemm_o(const unsigned short* __restrict__ A,
                                                 const unsigned short* __restrict__ Bt,
                                                 const float* __restrict__ bias,
                                                 float* __restrict__ C) {
  const f32x4 fz = {0.f, 0.f, 0.f, 0.f};
  f32x4 acc[4][4];
#pragma unroll
  for (int i = 0; i < 4; ++i)
#pragma unroll
    for (int j = 0; j < 4; ++j) acc[i][j] = fz;
  GEMM_PROLOG(A, Bt)
  GEMM_KLOOP(1)
#pragma unroll
  for (int j = 0; j < 4; ++j) {
    const int nb = n0 + wc * 64 + j * 16 + g * 4;
    const f32x4 b4 = *(const f32x4*)(const void*)(bias + nb);
#pragma unroll
    for (int i = 0; i < 4; ++i) {
      const int m = m0 + wr * 64 + i * 16 + r;
      f32x4 c;
#pragma unroll
      for (int t = 0; t < 4; ++t) c[t] = acc[i][j][t] + b4[t];
      *(f32x4*)(void*)(C + (size_t)m * 1024 + nb) = c;
    }
  }
}

// ---------------- fused attention with q-tile chaining ----------------
// grid 512 = 64 bh x 8 chains; each block owns 4 q-tiles (256 rows).
// Sweep schedule per block: passA(t0) | passB(t0)+passA(t1) | passB(t1)+passA(t2) |
// passB(t2)+passA(t3) | passB(t3)  -> 5 K-sweeps instead of 8, kf/mask shared in
// fused sweeps, and pass-A compute overlaps pass-B store stalls in-stream.
// Q pre-scaled by 0.125*log2e; no max subtraction; 1/L folded as cL=-log2(L).
#define LOADQF(dst, qrow0)                                                        \
  _Pragma("unroll")                                                               \
  for (int qc = 0; qc < 4; ++qc)                                                  \
    _Pragma("unroll")                                                             \
    for (int hf = 0; hf < 2; ++hf)                                                \
      dst[qc][hf] = *(const bf16x8*)(const void*)(Qb + (size_t)((qrow0) + qc * 16 + r) * 64 + hf * 32 + g * 8);

#define LOADKF(kf, kk)                                                            \
  _Pragma("unroll")                                                               \
  for (int ks = 0; ks < 2; ++ks)                                                  \
    _Pragma("unroll")                                                             \
    for (int hf = 0; hf < 2; ++hf)                                                \
      kf[ks][hf] = *(const bf16x8*)(const void*)(Kb + (size_t)((kk) + ks * 16 + r) * 64 + hf * 32 + g * 8);

#define LOADMP(mp0, mp1, kk)                                                      \
  {                                                                               \
    f32x4 mv0 = *(const f32x4*)(const void*)(mb + (kk) + g * 4);                  \
    f32x4 mv1 = *(const f32x4*)(const void*)(mb + (kk) + 16 + g * 4);             \
    _Pragma("unroll")                                                             \
    for (int j = 0; j < 4; ++j) { mp0[j] = mv0[j] * NEGM; mp1[j] = mv1[j] * NEGM; } \
  }

#define PASSA_CORE(qf, lreg, kf, mp0, mp1)                                        \
  _Pragma("unroll")                                                               \
  for (int qc = 0; qc < 4; ++qc) {                                                \
    f32x4 s0 = fz, s1 = fz;                                                       \
    s0 = mfma16(kf[0][0], qf[qc][0], s0);                                         \
    s0 = mfma16(kf[0][1], qf[qc][1], s0);                                         \
    s1 = mfma16(kf[1][0], qf[qc][0], s1);                                         \
    s1 = mfma16(kf[1][1], qf[qc][1], s1);                                         \
    float p = 0.f;                                                                \
    _Pragma("unroll")                                                             \
    for (int j = 0; j < 4; ++j) p += e2(s0[j] + mp0[j]) + e2(s1[j] + mp1[j]);     \
    lreg[qc] += p;                                                                \
  }

#define PASSB_CORE(qf, cL, oacc, kf, mp0, mp1, qrow, kk)                          \
  {                                                                               \
    _Pragma("unroll")                                                             \
    for (int ks = 0; ks < 2; ++ks) {                                              \
      _Pragma("unroll")                                                           \
      for (int qc = 0; qc < 4; ++qc) {                                            \
        f32x4 s = fz;                                                             \
        s = mfma16(kf[ks][0], qf[qc][0], s);                                      \
        s = mfma16(kf[ks][1], qf[qc][1], s);                                      \
        f32x4 pv;                                                                 \
        u16x4 pb;                                                                 \
        _Pragma("unroll")                                                         \
        for (int j = 0; j < 4; ++j) {                                             \
          const float val = e2(s[j] + (ks ? mp1[j] : mp0[j]) + cL[qc]);           \
          pv[j] = val;                                                            \
          pb[j] = bfc(val);                                                       \
        }                                                                         \
        __builtin_nontemporal_store(                                              \
            pv, (f32x4*)(void*)(ab + (size_t)((qrow) + qc * 16 + r) * 2048 + (kk) + ks * 16 + g * 4)); \
        *(u16x4*)(void*)(&Plds[w][(qc * 16 + r) * 40 + ks * 16 + g * 4]) = pb;    \
      }                                                                           \
    }                                                                             \
    bf16x8 vf[4];                                                                 \
    _Pragma("unroll")                                                             \
    for (int dn = 0; dn < 4; ++dn)                                                \
      vf[dn] = *(const bf16x8*)(const void*)(Vb + (size_t)(dn * 16 + r) * 2048 + (kk) + g * 8); \
    _Pragma("unroll")                                                             \
    for (int qs = 0; qs < 4; ++qs) {                                              \
      const bf16x8 pa = *(const bf16x8*)(const void*)(&Plds[w][(qs * 16 + r) * 40 + g * 8]); \
      _Pragma("unroll")                                                           \
      for (int dn = 0; dn < 4; ++dn) oacc[qs][dn] = mfma16(pa, vf[dn], oacc[qs][dn]); \
    }                                                                             \
  }

#define REDUCE_L(lreg)                                                            \
  _Pragma("unroll")                                                               \
  for (int qc = 0; qc < 4; ++qc) {                                                \
    lreg[qc] += __shfl_xor(lreg[qc], 16);                                         \
    lreg[qc] += __shfl_xor(lreg[qc], 32);                                         \
  }                                                                               \
  if (lane < 16) {                                                                \
    _Pragma("unroll")                                                             \
    for (int qc = 0; qc < 4; ++qc) sml[w][qc * 16 + lane] = lreg[qc];             \
  }

__global__ __launch_bounds__(256, 2) void attn_fused(const unsigned short* __restrict__ Qh,
                                                     const unsigned short* __restrict__ Kh,
                                                     const unsigned short* __restrict__ Vt,
                                                     const float* __restrict__ mask,
                                                     float* __restrict__ attn_out,
                                                     unsigned short* __restrict__ Obuf) {
  __shared__ unsigned short Plds[4][64 * 40];  // pad 40 -> only 2-way conflicts (free)
  __shared__ float Osum[64][68];
  __shared__ float sml[4][64];

  const int blk = (blockIdx.x & 7) * 64 + (blockIdx.x >> 3);  // XCD swizzle (512%8==0)
  const int bh = blk >> 3;
  const int q0base = (blk & 7) << 8;  // chain of 4 q-tiles = 256 rows
  const int b = bh >> 4, h = bh & 15;
  const int tid = threadIdx.x;
  const int w = tid >> 6, lane = tid & 63, g = lane >> 4, r = lane & 15;
  const float NEGM = -1e9f * LOG2E;

  const unsigned short* Qb = Qh + (size_t)bh * (2048 * 64);
  const unsigned short* Kb = Kh + (size_t)bh * (2048 * 64);
  const unsigned short* Vb = Vt + (size_t)bh * (64 * 2048);
  const float* mb = mask + (size_t)b * 2048;
  const f32x4 fz = {0.f, 0.f, 0.f, 0.f};
  float* ab = attn_out + (size_t)bh * 2048 * 2048;

  bf16x8 qfE[4][2], qfO[4][2];
  LOADQF(qfE, q0base)

  // ---- sweep 0: pure pass A for tile 0 ----
  {
    float lreg0[4] = {0.f, 0.f, 0.f, 0.f};
    for (int step = 0; step < 16; ++step) {
      const int kk = (w << 9) + (step << 5);
      bf16x8 kf[2][2];
      LOADKF(kf, kk)
      f32x4 mp0, mp1;
      LOADMP(mp0, mp1, kk)
      PASSA_CORE(qfE, lreg0, kf, mp0, mp1)
    }
    REDUCE_L(lreg0)
  }
  __syncthreads();

#pragma unroll
  for (int t = 0; t < 4; ++t) {
    bf16x8(&qa)[4][2] = (t & 1) ? qfO : qfE;
    bf16x8(&qb)[4][2] = (t & 1) ? qfE : qfO;
    const int qrow = q0base + t * 64;

    float cL[4];
#pragma unroll
    for (int qc = 0; qc < 4; ++qc) {
      const int q = qc * 16 + r;
      cL[qc] = -__log2f(sml[0][q] + sml[1][q] + sml[2][q] + sml[3][q]);
    }

    f32x4 oacc[4][4];
#pragma unroll
    for (int i = 0; i < 4; ++i)
#pragma unroll
      for (int j = 0; j < 4; ++j) oacc[i][j] = fz;

    float lregB[4] = {0.f, 0.f, 0.f, 0.f};
    if (t < 3) { LOADQF(qb, qrow + 64) }

    // ---- fused sweep: pass B (tile t) + pass A (tile t+1), kf/mask shared ----
    for (int step = 0; step < 16; ++step) {
      const int kk = (w << 9) + (step << 5);
      bf16x8 kf[2][2];
      LOADKF(kf, kk)
      f32x4 mp0, mp1;
      LOADMP(mp0, mp1, kk)
      PASSB_CORE(qa, cL, oacc, kf, mp0, mp1, qrow, kk)
      if (t < 3) { PASSA_CORE(qb, lregB, kf, mp0, mp1) }
    }
    if (t < 3) { REDUCE_L(lregB) }

    // ---- reduce O across waves (disjoint 512-key partials) ----
    for (int wv = 0; wv < 4; ++wv) {
      if (w == wv) {
#pragma unroll
        for (int qs = 0; qs < 4; ++qs)
#pragma unroll
          for (int dn = 0; dn < 4; ++dn)
#pragma unroll
            for (int j = 0; j < 4; ++j) {
              const int q = qs * 16 + g * 4 + j, d = dn * 16 + r;
              if (wv == 0) Osum[q][d] = oacc[qs][dn][j];
              else         Osum[q][d] += oacc[qs][dn][j];
            }
      }
      __syncthreads();
    }
    const int orow = tid >> 2, oc0 = (tid & 3) << 4;
#pragma unroll
    for (int half = 0; half < 2; ++half) {
      u16x8 pk;
#pragma unroll
      for (int j = 0; j < 8; ++j) pk[j] = bfc(Osum[orow][oc0 + half * 8 + j]);
      *(u16x8*)(void*)(Obuf + (size_t)(b * 2048 + qrow + orow) * 1024 + h * 64 + oc0 + half * 8) = pk;
    }
    __syncthreads();  // protect Osum/sml before next tile's writes
  }
}

// ---------------- launch ----------------
extern "C" void kernel_launch(void* const* d_in, const int* in_sizes, int n_in,
                              void* d_out, int out_size, void* d_ws, size_t ws_size,
                              hipStream_t stream) {
  const float* query = (const float*)d_in[0];
  const float* key_  = (const float*)d_in[1];
  const float* value = (const float*)d_in[2];
  const float* mask  = (const float*)d_in[3];
  const float* Wq = (const float*)d_in[4];
  const float* bq = (const float*)d_in[5];
  const float* Wk = (const float*)d_in[6];
  const float* bk = (const float*)d_in[7];
  const float* Wv = (const float*)d_in[8];
  const float* bv = (const float*)d_in[9];
  const float* Wo = (const float*)d_in[10];
  const float* bo = (const float*)d_in[11];

  uint8_t* ws = (uint8_t*)d_ws;
  unsigned short* XQ  = (unsigned short*)(ws);             // 16 MB bf16
  unsigned short* XK  = (unsigned short*)(ws + 16777216);
  unsigned short* XV  = (unsigned short*)(ws + 33554432);
  unsigned short* WTQ = (unsigned short*)(ws + 50331648);  // 2 MB each, [n][k]
  unsigned short* WTK = (unsigned short*)(ws + 52428800);
  unsigned short* WTV = (unsigned short*)(ws + 54525952);
  unsigned short* WTO = (unsigned short*)(ws + 56623104);
  unsigned short* QH  = (unsigned short*)(ws + 58720256);  // [bh][s][d] (pre-scaled)
  unsigned short* KH  = (unsigned short*)(ws + 75497472);  // [bh][s][d]
  unsigned short* VT  = (unsigned short*)(ws + 92274688);  // [bh][d][s]
  unsigned short* OB  = XQ;  // alias: XQ dead after gemm_qk

  float* outp = (float*)d_out;
  float* attnp = outp + 8388608;

  Ptr3 pc = {{query, key_, value}, {XQ, XK, XV}};
  cvt3<<<dim3(8192, 1, 3), 256, 0, stream>>>(pc);
  Ptr4 pw = {{Wq, Wk, Wv, Wo}, {WTQ, WTK, WTV, WTO}};
  wtrans4<<<dim3(32, 32, 4), 256, 0, stream>>>(pw);
  QKArgs qk = {{XQ, XK}, {WTQ, WTK}, {bq, bk}, {QH, KH}};
  gemm_qk<<<dim3(64, 8, 2), 256, 0, stream>>>(qk);
  gemm_v<<<dim3(64, 8), 256, 0, stream>>>(XV, WTV, bv, VT);
  attn_fused<<<512, 256, 0, stream>>>(QH, KH, VT, mask, attnp, OB);
  gemm_o<<<dim3(64, 8), 256, 0, stream>>>(OB, WTO, bo, outp);
}